// Round 1
// baseline (140.081 us; speedup 1.0000x reference)
//
#include <hip/hip_runtime.h>
#include <math.h>

#define EPSF 1e-6f

typedef __attribute__((ext_vector_type(8))) short bf16x8;   // 8 bf16 = 4 VGPR (MFMA A/B frag)
typedef __attribute__((ext_vector_type(4))) float f32x4;    // MFMA C/D frag
typedef __attribute__((ext_vector_type(4))) unsigned short u16x4;
typedef __attribute__((ext_vector_type(8))) unsigned short u16x8;

constexpr int TT = 256, MT = 2000, NP = 7200;

static __device__ __forceinline__ unsigned short f2bf(float f) {
    unsigned int u = __float_as_uint(f);
    u += 0x7FFFu + ((u >> 16) & 1u);
    return (unsigned short)(u >> 16);
}
static __device__ __forceinline__ float frcp(float x) { return __builtin_amdgcn_rcpf(x); }

// ---------------- Kernel 1: fused prep (unchanged) ----------------
__global__ __launch_bounds__(256) void prep_kernel(const float* __restrict__ logits,
                                                   const float* __restrict__ lab,
                                                   unsigned short* __restrict__ probs,
                                                   unsigned short* __restrict__ nlab) {
    int b = blockIdx.x;
    if (b < 900) {
        int i = (b * 256 + threadIdx.x) * 8;
        float4 x0 = *reinterpret_cast<const float4*>(logits + i);
        float4 x1 = *reinterpret_cast<const float4*>(logits + i + 4);
        float v[8] = {x0.x, x0.y, x0.z, x0.w, x1.x, x1.y, x1.z, x1.w};
        u16x8 o;
#pragma unroll
        for (int j = 0; j < 8; ++j) {
            float s = frcp(1.0f + __expf(-v[j]));
            s = fminf(fmaxf(s, EPSF), 1.0f - EPSF);
            o[j] = f2bf(s);
        }
        *reinterpret_cast<u16x8*>(probs + i) = o;
    } else {
        int wave = threadIdx.x >> 6;
        int lane = threadIdx.x & 63;
        int m = (b - 900) * 4 + wave;               // [0,2000)
        float4 v = reinterpret_cast<const float4*>(lab)[m * (TT / 4) + lane];
        float s = v.x + v.y + v.z + v.w;
#pragma unroll
        for (int off = 32; off > 0; off >>= 1) s += __shfl_down(s, off);
        float inv = frcp(__shfl(s, 0) + EPSF);
        u16x4 o;
        o[0] = f2bf(v.x * inv); o[1] = f2bf(v.y * inv);
        o[2] = f2bf(v.z * inv); o[3] = f2bf(v.w * inv);
        *reinterpret_cast<u16x4*>(nlab + m * TT + lane * 4) = o;
    }
}

// ---------------- Kernel 2: direct-from-L2 MFMA (no LDS, no barriers) ----------------
// Inputs are L2-resident by construction (A slab ~0.5 MB/XCD + B 1 MB with the XCD
// slab swizzle; R6 confirmed FETCH ~6 MB). LDS staging + 3 barriers + the
// register-held prefetch were pure overhead (guide Common-mistake #7). Each lane
// now loads its MFMA fragments straight from global (16B/lane, L2-hit), waves
// free-run with zero synchronization. Epilogue box loads issued after the K-loop
// so their live ranges don't overlap the main loop (register pressure down).
constexpr int NTX = 113, NTY = 32;                  // 3616 tiles, 64x64 each

__global__ __launch_bounds__(256) void cost_mfma_kernel(
    const unsigned short* __restrict__ A,   // probs bf16 [NP][TT]
    const unsigned short* __restrict__ B,   // nlab  bf16 [MT][TT]
    const float* __restrict__ pbox,         // [NP][4] cxcywh
    const float* __restrict__ tbox,         // [MT][4] cxcywh
    float* __restrict__ out)                // [NP][MT] fp32
{
    // XCD slab swizzle: XCD c gets contiguous l-range -> A-slab + all-B in its L2.
    int n = blockIdx.x;
    int l = (n & 7) * 452 + (n >> 3);
    const int n0 = (l >> 5) * 64;
    const int m0 = (l & 31) * 64;

    const int tid = threadIdx.x;
    const int lane = tid & 63, wave = tid >> 6;
    const int wr = wave & 1, wc = wave >> 1;        // wave's 32x32 quadrant
    const int fr = lane & 15, quad = lane >> 4;     // fragment row / k-quad

    // Fragment row base pointers (clamped; duplicates discarded at store).
    const unsigned short* ap[2];
    const unsigned short* bp[2];
#pragma unroll
    for (int t = 0; t < 2; ++t) {
        int ga = n0 + wr * 32 + t * 16 + fr; if (ga > NP - 1) ga = NP - 1;
        int gb = m0 + wc * 32 + t * 16 + fr; if (gb > MT - 1) gb = MT - 1;
        ap[t] = A + ga * TT + quad * 8;
        bp[t] = B + gb * TT + quad * 8;
    }

    f32x4 acc[2][2] = {};
#pragma unroll
    for (int kk = 0; kk < 8; ++kk) {                // K = 256 = 8 x 32
        bf16x8 af[2], bg[2];
#pragma unroll
        for (int t = 0; t < 2; ++t) {
            af[t] = *reinterpret_cast<const bf16x8*>(ap[t] + kk * 32);
            bg[t] = *reinterpret_cast<const bf16x8*>(bp[t] + kk * 32);
        }
#pragma unroll
        for (int ti = 0; ti < 2; ++ti)
#pragma unroll
            for (int tj = 0; tj < 2; ++tj)
                acc[ti][tj] = __builtin_amdgcn_mfma_f32_16x16x32_bf16(
                    af[ti], bg[tj], acc[ti][tj], 0, 0, 0);
    }

    // -------- epilogue: box costs + store --------
    float bcx[2], bcy[2], bww[2], bhh[2], bx1[2], by1[2], bx2[2], by2[2], areaB[2];
    int mj[2]; bool mv[2];
#pragma unroll
    for (int tj = 0; tj < 2; ++tj) {
        int gm = m0 + wc * 32 + tj * 16 + fr;
        mv[tj] = gm < MT; mj[tj] = gm;
        int g = mv[tj] ? gm : MT - 1;
        float4 b = *reinterpret_cast<const float4*>(&tbox[g * 4]);
        bcx[tj] = b.x; bcy[tj] = b.y; bww[tj] = b.z; bhh[tj] = b.w;
        bx1[tj] = b.x - 0.5f * b.z; by1[tj] = b.y - 0.5f * b.w;
        bx2[tj] = b.x + 0.5f * b.z; by2[tj] = b.y + 0.5f * b.w;
        areaB[tj] = (bx2[tj] - bx1[tj]) * (by2[tj] - by1[tj]);
    }

#pragma unroll
    for (int ti = 0; ti < 2; ++ti) {
#pragma unroll
        for (int r = 0; r < 4; ++r) {
            int p = n0 + wr * 32 + ti * 16 + quad * 4 + r;   // C/D: row = quad*4 + reg
            if (p >= NP) continue;
            float4 pb4 = *reinterpret_cast<const float4*>(&pbox[p * 4]);
            float ax1 = pb4.x - 0.5f * pb4.z, ay1 = pb4.y - 0.5f * pb4.w;
            float ax2 = pb4.x + 0.5f * pb4.z, ay2 = pb4.y + 0.5f * pb4.w;
            float areaA = (ax2 - ax1) * (ay2 - ay1);
#pragma unroll
            for (int tj = 0; tj < 2; ++tj) {
                if (!mv[tj]) continue;
                float l1 = fabsf(pb4.x - bcx[tj]) + fabsf(pb4.y - bcy[tj]) +
                           fabsf(pb4.z - bww[tj]) + fabsf(pb4.w - bhh[tj]);
                float ltx = fmaxf(ax1, bx1[tj]), lty = fmaxf(ay1, by1[tj]);
                float rbx = fminf(ax2, bx2[tj]), rby = fminf(ay2, by2[tj]);
                float iw = fmaxf(rbx - ltx, 0.0f), ih = fmaxf(rby - lty, 0.0f);
                float inter = iw * ih;
                float uni = areaA + areaB[tj] - inter;
                float iou = inter * frcp(uni + EPSF);
                float ex1 = fminf(ax1, bx1[tj]), ey1 = fminf(ay1, by1[tj]);
                float ex2 = fmaxf(ax2, bx2[tj]), ey2 = fmaxf(ay2, by2[tj]);
                float ew = fmaxf(ex2 - ex1, 0.0f), eh = fmaxf(ey2 - ey1, 0.0f);
                float areaE = ew * eh;
                float giou = iou - (areaE - uni) * frcp(areaE + EPSF);
                float res = 5.0f * l1 - acc[ti][tj][r] - 2.0f * fmaxf(giou, -1.0f);
                out[p * MT + mj[tj]] = res;
            }
        }
    }
}

extern "C" void kernel_launch(void* const* d_in, const int* in_sizes, int n_in,
                              void* d_out, int out_size, void* d_ws, size_t ws_size,
                              hipStream_t stream) {
    const float* pred_logits = (const float*)d_in[0];  // [8,900,256]
    const float* pred_boxes  = (const float*)d_in[1];  // [8,900,4]
    const float* tgt_boxes   = (const float*)d_in[2];  // [2000,4]
    const float* tgt_labels  = (const float*)d_in[3];  // [2000,256]
    float* out = (float*)d_out;                        // [7200,2000]

    unsigned short* probs = (unsigned short*)d_ws;     // 7200*256 bf16 (3.7 MB)
    unsigned short* nlab  = probs + NP * TT;           // 2000*256 bf16 (1.0 MB)

    prep_kernel<<<900 + 500, 256, 0, stream>>>(pred_logits, tgt_labels, probs, nlab);

    cost_mfma_kernel<<<NTX * NTY, 256, 0, stream>>>(probs, nlab, pred_boxes, tgt_boxes, out);
}

// Round 2
// 111.033 us; speedup vs baseline: 1.2616x; 1.2616x over previous
//
#include <hip/hip_runtime.h>
#include <math.h>

#define EPSF 1e-6f

typedef __attribute__((ext_vector_type(8))) short bf16x8;   // 8 bf16 = 4 VGPR (MFMA A/B frag)
typedef __attribute__((ext_vector_type(4))) float f32x4;    // MFMA C/D frag
typedef __attribute__((ext_vector_type(4))) unsigned short u16x4;
typedef __attribute__((ext_vector_type(8))) unsigned short u16x8;

constexpr int TT = 256, MT = 2000, NP = 7200;

static __device__ __forceinline__ unsigned short f2bf(float f) {
    unsigned int u = __float_as_uint(f);
    u += 0x7FFFu + ((u >> 16) & 1u);
    return (unsigned short)(u >> 16);
}
static __device__ __forceinline__ float frcp(float x) { return __builtin_amdgcn_rcpf(x); }

// Async global->LDS, 16B per lane. LDS dest must be wave-uniform (HW adds lane*16).
static __device__ __forceinline__ void gload_lds16(const unsigned short* g, unsigned short* l) {
    __builtin_amdgcn_global_load_lds(
        (const __attribute__((address_space(1))) unsigned int*)(g),
        (__attribute__((address_space(3))) unsigned int*)(l),
        16, 0, 0);
}

// ---------------- Kernel 1: fused prep (unchanged) ----------------
__global__ __launch_bounds__(256) void prep_kernel(const float* __restrict__ logits,
                                                   const float* __restrict__ lab,
                                                   unsigned short* __restrict__ probs,
                                                   unsigned short* __restrict__ nlab) {
    int b = blockIdx.x;
    if (b < 900) {
        int i = (b * 256 + threadIdx.x) * 8;
        float4 x0 = *reinterpret_cast<const float4*>(logits + i);
        float4 x1 = *reinterpret_cast<const float4*>(logits + i + 4);
        float v[8] = {x0.x, x0.y, x0.z, x0.w, x1.x, x1.y, x1.z, x1.w};
        u16x8 o;
#pragma unroll
        for (int j = 0; j < 8; ++j) {
            float s = frcp(1.0f + __expf(-v[j]));
            s = fminf(fmaxf(s, EPSF), 1.0f - EPSF);
            o[j] = f2bf(s);
        }
        *reinterpret_cast<u16x8*>(probs + i) = o;
    } else {
        int wave = threadIdx.x >> 6;
        int lane = threadIdx.x & 63;
        int m = (b - 900) * 4 + wave;               // [0,2000)
        float4 v = reinterpret_cast<const float4*>(lab)[m * (TT / 4) + lane];
        float s = v.x + v.y + v.z + v.w;
#pragma unroll
        for (int off = 32; off > 0; off >>= 1) s += __shfl_down(s, off);
        float inv = frcp(__shfl(s, 0) + EPSF);
        u16x4 o;
        o[0] = f2bf(v.x * inv); o[1] = f2bf(v.y * inv);
        o[2] = f2bf(v.z * inv); o[3] = f2bf(v.w * inv);
        *reinterpret_cast<u16x4*>(nlab + m * TT + lane * 4) = o;
    }
}

// ---------------- Kernel 2: single-barrier full-K MFMA ----------------
// 64x64 tile, K=256 staged in ONE shot via global_load_lds (16B width):
//   issue 16 gl_lds/thread -> vmcnt(0) -> ONE s_barrier -> 32 MFMA -> epilogue.
// No reg round-trip, no ds_write, no chunk barriers (R1 showed direct-L2 frag
// loads are latency-bound; R0 had 3 barriers + reg staging).
// LDS is linear [64][256] (gl_lds requires it); the 16-way ds_read_b128 bank
// conflict is fixed by XOR-swizzling BOTH the global source column and the
// ds_read column with ((row&7)<<4) bytes (rule #21: both-sides-or-neither).
// Residual 2-way conflict is free (m136). 64KB LDS -> 2 blocks/CU overlap.
constexpr int NTX = 113, NTY = 32;                  // 3616 tiles, 64x64 each

__global__ __launch_bounds__(256) void cost_mfma_kernel(
    const unsigned short* __restrict__ A,   // probs bf16 [NP][TT]
    const unsigned short* __restrict__ B,   // nlab  bf16 [MT][TT]
    const float* __restrict__ pbox,         // [NP][4] cxcywh
    const float* __restrict__ tbox,         // [MT][4] cxcywh
    float* __restrict__ out)                // [NP][MT] fp32
{
    __shared__ __align__(16) unsigned short As[64 * 256];   // 32 KB, linear
    __shared__ __align__(16) unsigned short Bs[64 * 256];   // 32 KB, linear

    // XCD slab swizzle: XCD c gets contiguous l-range -> A-slab + all-B in its L2.
    int n = blockIdx.x;
    int l = (n & 7) * 452 + (n >> 3);
    const int n0 = (l >> 5) * 64;
    const int m0 = (l & 31) * 64;

    const int tid = threadIdx.x;
    const int lane = tid & 63, wave = tid >> 6;
    const int wr = wave & 1, wc = wave >> 1;        // wave's 32x32 quadrant
    const int fr = lane & 15, quad = lane >> 4;     // fragment row / k-quad

    // ---- epilogue box prefetch (issued first; lands under the same vmcnt(0)) ----
    float4 tb[2]; int mj[2]; bool mv[2];
#pragma unroll
    for (int tj = 0; tj < 2; ++tj) {
        int gm = m0 + wc * 32 + tj * 16 + fr;
        mv[tj] = gm < MT; mj[tj] = gm;
        int g = mv[tj] ? gm : MT - 1;
        tb[tj] = *reinterpret_cast<const float4*>(&tbox[g * 4]);
    }
    float4 pbv[2][4]; int pr[2][4];
#pragma unroll
    for (int ti = 0; ti < 2; ++ti)
#pragma unroll
        for (int r = 0; r < 4; ++r) {
            int p = n0 + wr * 32 + ti * 16 + quad * 4 + r;   // C/D: row = quad*4 + reg
            pr[ti][r] = p;
            int g = p < NP ? p : NP - 1;
            pbv[ti][r] = *reinterpret_cast<const float4*>(&pbox[g * 4]);
        }

    // ---- stage full K=256: wave w covers rows [w*16, w*16+16) of A and B ----
    // One gl_lds issue = 64 lanes x 16B = 1 KB = 2 LDS rows (512 B each).
    // lane -> (row = base + lane>>5, chunk = lane&31). Global column is
    // pre-swizzled so the linear LDS write realizes the swizzled layout.
    {
        const int lro = lane >> 5;                  // 0/1: row within the 1KB issue
        const int lch = lane & 31;                  // 16B chunk within the 512B row
#pragma unroll
        for (int i = 0; i < 8; ++i) {
            int row = wave * 16 + i * 2 + lro;
            int cs = (lch * 16) ^ ((row & 7) << 4); // swizzled byte column
            int gn = n0 + row; gn = gn > NP - 1 ? NP - 1 : gn;
            int gm = m0 + row; gm = gm > MT - 1 ? MT - 1 : gm;
            gload_lds16(A + gn * TT + (cs >> 1), &As[wave * 4096 + i * 512]);
            gload_lds16(B + gm * TT + (cs >> 1), &Bs[wave * 4096 + i * 512]);
        }
    }
    __syncthreads();   // vmcnt(0) + barrier: the ONLY barrier in the kernel

    // ---- 32 MFMAs over K=256 (swizzled ds_read_b128) ----
    const char* aB[2]; const char* bB[2];
    const int xs = (fr & 7) << 4;                   // row&7 == fr&7 for our rows
#pragma unroll
    for (int t = 0; t < 2; ++t) {
        aB[t] = reinterpret_cast<const char*>(As) + (wr * 32 + t * 16 + fr) * 512;
        bB[t] = reinterpret_cast<const char*>(Bs) + (wc * 32 + t * 16 + fr) * 512;
    }

    f32x4 acc[2][2] = {};
#pragma unroll
    for (int kk = 0; kk < 8; ++kk) {
        int cb = (kk * 64 + quad * 16) ^ xs;        // swizzled byte column
        bf16x8 af[2], bg[2];
#pragma unroll
        for (int t = 0; t < 2; ++t) {
            af[t] = *reinterpret_cast<const bf16x8*>(aB[t] + cb);
            bg[t] = *reinterpret_cast<const bf16x8*>(bB[t] + cb);
        }
#pragma unroll
        for (int ti = 0; ti < 2; ++ti)
#pragma unroll
            for (int tj = 0; tj < 2; ++tj)
                acc[ti][tj] = __builtin_amdgcn_mfma_f32_16x16x32_bf16(
                    af[ti], bg[tj], acc[ti][tj], 0, 0, 0);
    }

    // -------- epilogue from prefetched registers --------
    float bcx[2], bcy[2], bww[2], bhh[2], bx1[2], by1[2], bx2[2], by2[2], areaB[2];
#pragma unroll
    for (int tj = 0; tj < 2; ++tj) {
        float4 b = tb[tj];
        bcx[tj] = b.x; bcy[tj] = b.y; bww[tj] = b.z; bhh[tj] = b.w;
        bx1[tj] = b.x - 0.5f * b.z; by1[tj] = b.y - 0.5f * b.w;
        bx2[tj] = b.x + 0.5f * b.z; by2[tj] = b.y + 0.5f * b.w;
        areaB[tj] = (bx2[tj] - bx1[tj]) * (by2[tj] - by1[tj]);
    }

#pragma unroll
    for (int ti = 0; ti < 2; ++ti) {
#pragma unroll
        for (int r = 0; r < 4; ++r) {
            int p = pr[ti][r];
            if (p >= NP) continue;
            float4 pb4 = pbv[ti][r];
            float ax1 = pb4.x - 0.5f * pb4.z, ay1 = pb4.y - 0.5f * pb4.w;
            float ax2 = pb4.x + 0.5f * pb4.z, ay2 = pb4.y + 0.5f * pb4.w;
            float areaA = (ax2 - ax1) * (ay2 - ay1);
#pragma unroll
            for (int tj = 0; tj < 2; ++tj) {
                if (!mv[tj]) continue;
                float l1 = fabsf(pb4.x - bcx[tj]) + fabsf(pb4.y - bcy[tj]) +
                           fabsf(pb4.z - bww[tj]) + fabsf(pb4.w - bhh[tj]);
                float ltx = fmaxf(ax1, bx1[tj]), lty = fmaxf(ay1, by1[tj]);
                float rbx = fminf(ax2, bx2[tj]), rby = fminf(ay2, by2[tj]);
                float iw = fmaxf(rbx - ltx, 0.0f), ih = fmaxf(rby - lty, 0.0f);
                float inter = iw * ih;
                float uni = areaA + areaB[tj] - inter;
                float iou = inter * frcp(uni + EPSF);
                float ex1 = fminf(ax1, bx1[tj]), ey1 = fminf(ay1, by1[tj]);
                float ex2 = fmaxf(ax2, bx2[tj]), ey2 = fmaxf(ay2, by2[tj]);
                float ew = fmaxf(ex2 - ex1, 0.0f), eh = fmaxf(ey2 - ey1, 0.0f);
                float areaE = ew * eh;
                float giou = iou - (areaE - uni) * frcp(areaE + EPSF);
                float res = 5.0f * l1 - acc[ti][tj][r] - 2.0f * fmaxf(giou, -1.0f);
                out[p * MT + mj[tj]] = res;
            }
        }
    }
}

extern "C" void kernel_launch(void* const* d_in, const int* in_sizes, int n_in,
                              void* d_out, int out_size, void* d_ws, size_t ws_size,
                              hipStream_t stream) {
    const float* pred_logits = (const float*)d_in[0];  // [8,900,256]
    const float* pred_boxes  = (const float*)d_in[1];  // [8,900,4]
    const float* tgt_boxes   = (const float*)d_in[2];  // [2000,4]
    const float* tgt_labels  = (const float*)d_in[3];  // [2000,256]
    float* out = (float*)d_out;                        // [7200,2000]

    unsigned short* probs = (unsigned short*)d_ws;     // 7200*256 bf16 (3.7 MB)
    unsigned short* nlab  = probs + NP * TT;           // 2000*256 bf16 (1.0 MB)

    prep_kernel<<<900 + 500, 256, 0, stream>>>(pred_logits, tgt_labels, probs, nlab);

    cost_mfma_kernel<<<NTX * NTY, 256, 0, stream>>>(probs, nlab, pred_boxes, tgt_boxes, out);
}